// Round 12
// baseline (709.531 us; speedup 1.0000x reference)
//
#include <hip/hip_runtime.h>
#include <hip/hip_bf16.h>

typedef __hip_bfloat16 bf16;
typedef __attribute__((ext_vector_type(8))) short short8;
typedef __attribute__((ext_vector_type(4))) short short4v;
typedef __attribute__((ext_vector_type(4))) float f32x4;

#define MFMA16(a, b, c) __builtin_amdgcn_mfma_f32_16x16x32_bf16((a), (b), (c), 0, 0, 0)

static __device__ __forceinline__ void gload_lds16(const bf16* g, bf16* l) {
  __builtin_amdgcn_global_load_lds((const __attribute__((address_space(1))) unsigned int*)g,
                                   (__attribute__((address_space(3))) unsigned int*)l,
                                   16, 0, 0);
}

// ---------------- cast x: fp32 -> bf16 ----------------
__global__ __launch_bounds__(256) void castx_kernel(const float* __restrict__ x,
                                                    bf16* __restrict__ xb, int n) {
  int i = (blockIdx.x * 256 + threadIdx.x) * 8;
  if (i >= n) return;
  float4 v0 = *(const float4*)(x + i);
  float4 v1 = *(const float4*)(x + i + 4);
  bf16 tmp[8];
  tmp[0] = __float2bfloat16(v0.x); tmp[1] = __float2bfloat16(v0.y);
  tmp[2] = __float2bfloat16(v0.z); tmp[3] = __float2bfloat16(v0.w);
  tmp[4] = __float2bfloat16(v1.x); tmp[5] = __float2bfloat16(v1.y);
  tmp[6] = __float2bfloat16(v1.z); tmp[7] = __float2bfloat16(v1.w);
  *(short8*)(xb + i) = *(short8*)tmp;
}

// ---------------- transpose+cast weight: W[K][N] fp32 -> WT[N][K] bf16 ----------------
__global__ __launch_bounds__(256) void tw_kernel(const float* __restrict__ W,
                                                 bf16* __restrict__ WT) {
  __shared__ bf16 tile[64][65];
  int b = blockIdx.x;
  int tk = (b >> 6) * 64;
  int tn = (b & 63) * 64;
  int t = threadIdx.x;
  int c = t & 63, r0 = t >> 6;
#pragma unroll
  for (int i = 0; i < 16; ++i) {
    int r = i * 4 + r0;
    tile[c][r] = __float2bfloat16(W[(size_t)(tk + r) * 4096 + tn + c]);
  }
  __syncthreads();
#pragma unroll
  for (int i = 0; i < 16; ++i) {
    int r = i * 4 + r0;
    WT[(size_t)(tn + r) * 4096 + tk + c] = tile[r][c];
  }
}

// ---------------- Fused Q+K GEMM: reduced-barrier + wave-parity stagger ----------------
// BM=BN=256, BK=64; 8 waves, wave 128x64. LDS 2 bufs x {A_k0,A_k1,B_k0,B_k1} [256][32].
// 2 barriers/K-tile (after counted vmcnt(4) drains). Within each kc-half, even waves
// process mi 0-3 then 4-7; odd waves 4-7 then 0-3 -> at any instant half the waves
// issue ds_reads while the other half runs MFMA (LDS/matrix-pipe overlap).
// 2D XCD chunk (4bm x 8bn per XCD). Epilogue: bn<16 -> Q (RoPE+scale), else K (RoPE).
__global__ __launch_bounds__(512) void gemmQK8(const bf16* __restrict__ A,
                                               const bf16* __restrict__ Bt,
                                               bf16* __restrict__ Qb,
                                               bf16* __restrict__ Kb,
                                               const float* __restrict__ fcos,
                                               const float* __restrict__ fsin) {
  __shared__ bf16 LDS[2 * 32768];  // 128 KB
  const int K = 4096, NK = 64;
  int g = blockIdx.x;
  int xcd = g & 7, loc = g >> 3;
  int bm = (xcd >> 2) * 4 + (loc >> 3);
  int bn = (xcd & 3) * 8 + (loc & 7);
  int t = threadIdx.x, lane = t & 63, w = t >> 6;
  int wm = w >> 2, wn = w & 3;
  int lr = lane & 15, lg = lane >> 4;
  int rsw = (lr >> 1) & 3;
  f32x4 acc[8][4] = {};

  const bf16* Ab = A + (size_t)bm * 256 * K;
  const bf16* Bb = Bt + (size_t)bn * 256 * K;
  int sr4 = t >> 2;
  int sg = (t & 3) ^ ((t >> 3) & 3);

#define SA(nb, kt2, kh)                                                          \
  do {                                                                           \
    _Pragma("unroll") for (int j = 0; j < 2; ++j)                                \
      gload_lds16(Ab + (size_t)(j * 128 + sr4) * K + (kt2) * 64 + (kh) * 32 + sg * 8, \
                  LDS + (nb) + (kh) * 8192 + (j * 512 + t) * 8);                 \
  } while (0)
#define SB(nb, kt2, kh)                                                          \
  do {                                                                           \
    _Pragma("unroll") for (int j = 0; j < 2; ++j)                                \
      gload_lds16(Bb + (size_t)(j * 128 + sr4) * K + (kt2) * 64 + (kh) * 32 + sg * 8, \
                  LDS + (nb) + 16384 + (kh) * 8192 + (j * 512 + t) * 8);         \
  } while (0)
#define AFR(base, kc, mi) \
  (*(const short8*)(LDS + (base) + (kc) * 8192 + (wm * 128 + (mi) * 16 + lr) * 32 + ((lg ^ rsw) << 3)))
#define BFR(base, kc, nf) \
  (*(const short8*)(LDS + (base) + 16384 + (kc) * 8192 + (wn * 64 + (nf) * 16 + lr) * 32 + ((lg ^ rsw) << 3)))

// one mi-quad: read 4 A-frags, MFMA 4x4 into acc rows [mi0..mi0+4)
#define QUAD(base, kc, mi0)                                                      \
  do {                                                                           \
    short8 a_[4];                                                                \
    _Pragma("unroll") for (int i = 0; i < 4; ++i) a_[i] = AFR(base, kc, (mi0) + i); \
    __builtin_amdgcn_s_setprio(1);                                               \
    _Pragma("unroll") for (int i = 0; i < 4; ++i)                                \
      _Pragma("unroll") for (int nf = 0; nf < 4; ++nf)                           \
        acc[(mi0) + i][nf] = MFMA16(a_[i], b[nf], acc[(mi0) + i][nf]);           \
    __builtin_amdgcn_s_setprio(0);                                               \
  } while (0)

  SA(0, 0, 0); SB(0, 0, 0); SA(0, 0, 1); SB(0, 0, 1);
  asm volatile("s_waitcnt vmcnt(4)" ::: "memory");
  __builtin_amdgcn_s_barrier();

  int cur = 0;
  for (int kt = 0; kt < NK; ++kt) {
    int base = cur * 32768;
    int nbf = (cur ^ 1) * 32768;
    bool pf = (kt + 1) < NK;
    short8 b[4];

    // ---- half kc=0 ----
#pragma unroll
    for (int nf = 0; nf < 4; ++nf) b[nf] = BFR(base, 0, nf);
    if (pf) SA(nbf, kt + 1, 0);
    if (w & 1) {
      QUAD(base, 0, 4);
      if (pf) SB(nbf, kt + 1, 0);
      QUAD(base, 0, 0);
    } else {
      QUAD(base, 0, 0);
      if (pf) SB(nbf, kt + 1, 0);
      QUAD(base, 0, 4);
    }
    if (pf)
      asm volatile("s_waitcnt vmcnt(4)" ::: "memory");  // drain this tile's A_k1,B_k1
    else
      asm volatile("s_waitcnt vmcnt(0)" ::: "memory");
    __builtin_amdgcn_s_barrier();

    // ---- half kc=1 ----
#pragma unroll
    for (int nf = 0; nf < 4; ++nf) b[nf] = BFR(base, 1, nf);
    if (pf) SA(nbf, kt + 1, 1);
    if (w & 1) {
      QUAD(base, 1, 4);
      if (pf) SB(nbf, kt + 1, 1);
      QUAD(base, 1, 0);
    } else {
      QUAD(base, 1, 0);
      if (pf) SB(nbf, kt + 1, 1);
      QUAD(base, 1, 4);
    }
    asm volatile("s_waitcnt vmcnt(4)" ::: "memory");  // drain next tile's A_k0,B_k0
    __builtin_amdgcn_s_barrier();

    cur ^= 1;
  }
#undef SA
#undef SB
#undef AFR
#undef BFR
#undef QUAD

  int sect = bn >> 4, bnl = bn & 15;
  bf16* Cb = sect ? Kb : Qb;
  const float qs = sect ? 1.0f : 0.08838834764831845f;
#pragma unroll
  for (int mi = 0; mi < 8; ++mi)
#pragma unroll
    for (int nf = 0; nf < 4; ++nf) {
      int col = bnl * 256 + wn * 64 + nf * 16 + lr;
      int row0 = bm * 256 + wm * 128 + mi * 16 + lg * 4;
      int ip = (col >> 1) & 63;
      float sgn = (col & 1) ? 1.0f : -1.0f;
#pragma unroll
      for (int r = 0; r < 4; ++r) {
        int row = row0 + r;
        float mine = acc[mi][nf][r];
        float oth = __shfl_xor(mine, 1);
        float cv = fcos[row * 64 + ip];
        float sv = fsin[row * 64 + ip];
        float v = (mine * cv + sgn * oth * sv) * qs;
        Cb[(size_t)row * 4096 + col] = __float2bfloat16(v);
      }
    }
}

// ---------------- gemmB: BM=128 BN=256, stagger + MFMA-before-barrier ----------
// 8 waves = 1x8, wave tile 128x32 (acc[8][2]); LDS 2 bufs x {A_k0,A_k1,B_k0,B_k1},
// 96 KB. 2 barriers/K-tile, vmcnt(3) counted drains placed AFTER the MFMA cluster.
// Wave-parity stagger of mi-quads as in gemmQK8.
// EPI: 3 = transposed store Vt[col][row] (bf16), 4 = fp32 store.
template <int EPI>
__global__ __launch_bounds__(512) void gemmB(const bf16* __restrict__ A,
                                             const bf16* __restrict__ Bt,
                                             void* __restrict__ Cv,
                                             int M, int N) {
  __shared__ bf16 LDS[2 * 24576];  // 96 KB
  const int K = 4096, NK = 64;
  int g = blockIdx.x;
  int xcd = g & 7, loc = g >> 3;
  int bm = (xcd >> 1) * 4 + (loc >> 3);
  int bn = (xcd & 1) * 8 + (loc & 7);
  int t = threadIdx.x, lane = t & 63, w = t >> 6;
  int lr = lane & 15, lg = lane >> 4;
  int rsw = (lr >> 1) & 3;
  f32x4 acc[8][2] = {};

  const bf16* Ab = A + (size_t)bm * 128 * K;
  const bf16* Bb = Bt + (size_t)bn * 256 * K;
  int sr4 = t >> 2;
  int sg = (t & 3) ^ ((t >> 3) & 3);

#define SAB(nb, kt2, kh)                                                         \
  gload_lds16(Ab + (size_t)sr4 * K + (kt2) * 64 + (kh) * 32 + sg * 8,            \
              LDS + (nb) + (kh) * 4096 + t * 8)
#define SBB(nb, kt2, kh)                                                         \
  do {                                                                           \
    _Pragma("unroll") for (int j = 0; j < 2; ++j)                                \
      gload_lds16(Bb + (size_t)(j * 128 + sr4) * K + (kt2) * 64 + (kh) * 32 + sg * 8, \
                  LDS + (nb) + 8192 + (kh) * 8192 + (j * 512 + t) * 8);          \
  } while (0)
#define AFRB(base, kc, mi) \
  (*(const short8*)(LDS + (base) + (kc) * 4096 + ((mi) * 16 + lr) * 32 + ((lg ^ rsw) << 3)))
#define BFRB(base, kc, nf) \
  (*(const short8*)(LDS + (base) + 8192 + (kc) * 8192 + (w * 32 + (nf) * 16 + lr) * 32 + ((lg ^ rsw) << 3)))

#define QUADB(base, kc, mi0)                                                     \
  do {                                                                           \
    short8 a_[4];                                                                \
    _Pragma("unroll") for (int i = 0; i < 4; ++i) a_[i] = AFRB(base, kc, (mi0) + i); \
    __builtin_amdgcn_s_setprio(1);                                               \
    _Pragma("unroll") for (int i = 0; i < 4; ++i)                                \
      _Pragma("unroll") for (int nf = 0; nf < 2; ++nf)                           \
        acc[(mi0) + i][nf] = MFMA16(a_[i], b[nf], acc[(mi0) + i][nf]);           \
    __builtin_amdgcn_s_setprio(0);                                               \
  } while (0)

  SAB(0, 0, 0); SBB(0, 0, 0); SAB(0, 0, 1); SBB(0, 0, 1);
  asm volatile("s_waitcnt vmcnt(3)" ::: "memory");
  __builtin_amdgcn_s_barrier();

  int cur = 0;
  for (int kt = 0; kt < NK; ++kt) {
    int base = cur * 24576;
    int nbf = (cur ^ 1) * 24576;
    bool pf = (kt + 1) < NK;
    short8 b[2];

    // ---- half kc=0 ----
    b[0] = BFRB(base, 0, 0); b[1] = BFRB(base, 0, 1);
    if (pf) SAB(nbf, kt + 1, 0);
    if (w & 1) {
      QUADB(base, 0, 4);
      if (pf) SBB(nbf, kt + 1, 0);
      QUADB(base, 0, 0);
    } else {
      QUADB(base, 0, 0);
      if (pf) SBB(nbf, kt + 1, 0);
      QUADB(base, 0, 4);
    }
    if (pf)
      asm volatile("s_waitcnt vmcnt(3)" ::: "memory");  // drain this tile's A_k1,B_k1
    else
      asm volatile("s_waitcnt vmcnt(0)" ::: "memory");
    __builtin_amdgcn_s_barrier();

    // ---- half kc=1 ----
    b[0] = BFRB(base, 1, 0); b[1] = BFRB(base, 1, 1);
    if (pf) SAB(nbf, kt + 1, 1);
    if (w & 1) {
      QUADB(base, 1, 4);
      if (pf) SBB(nbf, kt + 1, 1);
      QUADB(base, 1, 0);
    } else {
      QUADB(base, 1, 0);
      if (pf) SBB(nbf, kt + 1, 1);
      QUADB(base, 1, 4);
    }
    asm volatile("s_waitcnt vmcnt(3)" ::: "memory");  // drain next tile's A_k0,B_k0
    __builtin_amdgcn_s_barrier();

    cur ^= 1;
  }
#undef SAB
#undef SBB
#undef AFRB
#undef BFRB
#undef QUADB

#pragma unroll
  for (int mi = 0; mi < 8; ++mi)
#pragma unroll
    for (int nf = 0; nf < 2; ++nf) {
      int col = bn * 256 + w * 32 + nf * 16 + lr;
      int row0 = bm * 128 + mi * 16 + lg * 4;
      if constexpr (EPI == 3) {
        bf16 tmp[4];
#pragma unroll
        for (int r = 0; r < 4; ++r) tmp[r] = __float2bfloat16(acc[mi][nf][r]);
        *(short4v*)((bf16*)Cv + (size_t)col * M + row0) = *(short4v*)tmp;
      } else {
#pragma unroll
        for (int r = 0; r < 4; ++r)
          ((float*)Cv)[(size_t)(row0 + r) * N + col] = acc[mi][nf][r];
      }
    }
}

// ---------------- Flash attention v3 (unchanged) ----------------
__global__ __launch_bounds__(512, 2) void attn_fwd(const bf16* __restrict__ Q,
                                                   const bf16* __restrict__ K,
                                                   const bf16* __restrict__ Vt,
                                                   bf16* __restrict__ O) {
  __shared__ bf16 Kbuf[2][64 * 128];
  __shared__ bf16 Vbuf[2][128 * 64];
  __shared__ char Ps_all[8][2][2048];
  const int S = 2048, D = 4096, HD = 128, NT = 32;
  int g = blockIdx.y * 8 + blockIdx.x;
  int wid = (g & 7) * 32 + (g >> 3);
  int h = wid >> 3, qb = wid & 7;
  int tid = threadIdx.x, lane = tid & 63, w = tid >> 6;
  int lr = lane & 15, lg = lane >> 4;
  int q0 = qb * 256 + w * 32;
  int swz = (lr & 7) << 4;

  const bf16* Kh = K + h * HD;
  const bf16* Vh = Vt + (size_t)h * HD * S;

  short8 aq[2][4];
#pragma unroll
  for (int u = 0; u < 2; ++u)
#pragma unroll
    for (int c = 0; c < 4; ++c)
      aq[u][c] = *(const short8*)(Q + (size_t)(q0 + u * 16 + lr) * D + h * HD + c * 32 + lg * 8);

  int kr = lane >> 4, ksl = lane & 15;
  int vr = lane >> 3, vsl = lane & 7;

  f32x4 accO[2][8] = {};
  float lsum[2] = {0.f, 0.f};

#define STAGE(b, ttile)                                                            \
  do {                                                                             \
    int kv0_ = (ttile) * 64;                                                       \
    _Pragma("unroll") for (int ii = 0; ii < 2; ++ii) {                             \
      int row = w * 8 + ii * 4 + kr;                                               \
      gload_lds16(Kh + (size_t)(kv0_ + row) * D + ((ksl ^ (row & 7)) << 3),        \
                  &Kbuf[b][(w * 8 + ii * 4) * 128]);                               \
    }                                                                              \
    _Pragma("unroll") for (int ii = 0; ii < 2; ++ii) {                             \
      int row = w * 16 + ii * 8 + vr;                                              \
      gload_lds16(Vh + (size_t)row * S + kv0_ + ((vsl ^ (row & 7)) << 3),          \
                  &Vbuf[b][(w * 16 + ii * 8) * 64]);                               \
    }                                                                              \
  } while (0)

  int cur = 0;
  STAGE(0, 0);
  for (int tt = 0; tt < NT; ++tt) {
    if (tt + 1 < NT) {
      STAGE(cur ^ 1, tt + 1);
      asm volatile("s_waitcnt vmcnt(4)" ::: "memory");
    } else {
      asm volatile("s_waitcnt vmcnt(0)" ::: "memory");
    }
    __builtin_amdgcn_s_barrier();
    const bf16* Kb_ = Kbuf[cur];
    const bf16* Vb_ = Vbuf[cur];

    f32x4 sf[2][4] = {};
#pragma unroll
    for (int j = 0; j < 4; ++j)
#pragma unroll
      for (int c = 0; c < 4; ++c) {
        short8 kf = *(const short8*)(Kb_ + (j * 16 + lr) * 128 +
                                     (((c * 4 + lg) ^ (lr & 7)) << 3));
        sf[0][j] = MFMA16(kf, aq[0][c], sf[0][j]);
        sf[1][j] = MFMA16(kf, aq[1][c], sf[1][j]);
      }
#pragma unroll
    for (int u = 0; u < 2; ++u) {
      char* Ps = Ps_all[w][u];
#pragma unroll
      for (int j = 0; j < 4; ++j) {
        float p0 = __expf(sf[u][j][0]);
        float p1 = __expf(sf[u][j][1]);
        float p2 = __expf(sf[u][j][2]);
        float p3 = __expf(sf[u][j][3]);
        lsum[u] += (p0 + p1) + (p2 + p3);
        bf16 pk[4] = {__float2bfloat16(p0), __float2bfloat16(p1),
                      __float2bfloat16(p2), __float2bfloat16(p3)};
        *(short4v*)(Ps + lr * 128 + ((j * 32 + lg * 8) ^ swz)) = *(short4v*)pk;
      }
    }
#pragma unroll
    for (int t2 = 0; t2 < 2; ++t2) {
      short8 pa0 = *(const short8*)(Ps_all[w][0] + lr * 128 + ((t2 * 64 + lg * 16) ^ swz));
      short8 pa1 = *(const short8*)(Ps_all[w][1] + lr * 128 + ((t2 * 64 + lg * 16) ^ swz));
#pragma unroll
      for (int n = 0; n < 8; ++n) {
        short8 bv = *(const short8*)(Vb_ + (n * 16 + lr) * 64 +
                                     (((t2 * 4 + lg) ^ (lr & 7)) << 3));
        accO[0][n] = MFMA16(pa0, bv, accO[0][n]);
        accO[1][n] = MFMA16(pa1, bv, accO[1][n]);
      }
    }
    __builtin_amdgcn_s_barrier();
    cur ^= 1;
  }
#undef STAGE

#pragma unroll
  for (int u = 0; u < 2; ++u) {
    float ls = lsum[u];
    ls += __shfl_xor(ls, 16);
    ls += __shfl_xor(ls, 32);
    float rs[4];
#pragma unroll
    for (int r = 0; r < 4; ++r)
      rs[r] = 1.f / __shfl(ls, lg * 4 + r);
#pragma unroll
    for (int n = 0; n < 8; ++n)
#pragma unroll
      for (int r = 0; r < 4; ++r) {
        int row = q0 + u * 16 + lg * 4 + r;
        int col = h * HD + n * 16 + lr;
        O[(size_t)row * D + col] = __float2bfloat16(accO[u][n][r] * rs[r]);
      }
  }
}

extern "C" void kernel_launch(void* const* d_in, const int* in_sizes, int n_in,
                              void* d_out, int out_size, void* d_ws, size_t ws_size,
                              hipStream_t stream) {
  const float* x    = (const float*)d_in[0];
  const float* fcos = (const float*)d_in[1];
  const float* fsin = (const float*)d_in[2];
  const float* wq   = (const float*)d_in[3];
  const float* wk   = (const float*)d_in[4];
  const float* wv   = (const float*)d_in[5];
  const float* wo   = (const float*)d_in[6];
  float* out = (float*)d_out;

  const int S = 2048, D = 4096;
  const size_t MB = 1024 * 1024;
  char* ws = (char*)d_ws;
  bf16* xb  = (bf16*)(ws);            // [0,16)  x bf16; later AO
  bf16* wT2 = (bf16*)(ws + 16 * MB);  // [16,80) wq-T | wk-T; later wv-T / wo-T
  bf16* Vt  = (bf16*)(ws + 48 * MB);  // [48,80) Vt[h][d][s]
  bf16* Qb  = (bf16*)(ws + 80 * MB);  // [80,96)
  bf16* Kb  = (bf16*)(ws + 96 * MB);  // [96,112)
  bf16* AO  = (bf16*)(ws);            // reuse xb slot after QKV GEMMs

  int n = S * D;
  castx_kernel<<<n / (256 * 8), 256, 0, stream>>>(x, xb, n);

  // fused Q+K GEMM (N=8192), staggered schedule
  tw_kernel<<<4096, 256, 0, stream>>>(wq, wT2);
  tw_kernel<<<4096, 256, 0, stream>>>(wk, wT2 + (size_t)4096 * 4096);
  gemmQK8<<<256, 512, 0, stream>>>(xb, wT2, Qb, Kb, fcos, fsin);

  // V GEMM with transposed store (gemmB, 256 blocks)
  tw_kernel<<<4096, 256, 0, stream>>>(wv, wT2);
  gemmB<3><<<256, 512, 0, stream>>>(xb, wT2, Vt, S, D);

  attn_fwd<<<dim3(8, 32), 512, 0, stream>>>(Qb, Kb, Vt, AO);

  // output GEMM (fp32 out, gemmB, 256 blocks)
  tw_kernel<<<4096, 256, 0, stream>>>(wo, wT2);
  gemmB<4><<<256, 512, 0, stream>>>(AO, wT2, out, S, D);
}

// Round 13
// 538.419 us; speedup vs baseline: 1.3178x; 1.3178x over previous
//
#include <hip/hip_runtime.h>
#include <hip/hip_bf16.h>

typedef __hip_bfloat16 bf16;
typedef __attribute__((ext_vector_type(8))) short short8;
typedef __attribute__((ext_vector_type(4))) short short4v;
typedef __attribute__((ext_vector_type(4))) float f32x4;

#define MFMA16(a, b, c) __builtin_amdgcn_mfma_f32_16x16x32_bf16((a), (b), (c), 0, 0, 0)

static __device__ __forceinline__ void gload_lds16(const bf16* g, bf16* l) {
  __builtin_amdgcn_global_load_lds((const __attribute__((address_space(1))) unsigned int*)g,
                                   (__attribute__((address_space(3))) unsigned int*)l,
                                   16, 0, 0);
}

// ---------------- cast x: fp32 -> bf16 ----------------
__global__ __launch_bounds__(256) void castx_kernel(const float* __restrict__ x,
                                                    bf16* __restrict__ xb, int n) {
  int i = (blockIdx.x * 256 + threadIdx.x) * 8;
  if (i >= n) return;
  float4 v0 = *(const float4*)(x + i);
  float4 v1 = *(const float4*)(x + i + 4);
  bf16 tmp[8];
  tmp[0] = __float2bfloat16(v0.x); tmp[1] = __float2bfloat16(v0.y);
  tmp[2] = __float2bfloat16(v0.z); tmp[3] = __float2bfloat16(v0.w);
  tmp[4] = __float2bfloat16(v1.x); tmp[5] = __float2bfloat16(v1.y);
  tmp[6] = __float2bfloat16(v1.z); tmp[7] = __float2bfloat16(v1.w);
  *(short8*)(xb + i) = *(short8*)tmp;
}

// ---------------- transpose+cast weight: W[K][N] fp32 -> WT[N][K] bf16 ----------------
__global__ __launch_bounds__(256) void tw_kernel(const float* __restrict__ W,
                                                 bf16* __restrict__ WT) {
  __shared__ bf16 tile[64][65];
  int b = blockIdx.x;
  int tk = (b >> 6) * 64;
  int tn = (b & 63) * 64;
  int t = threadIdx.x;
  int c = t & 63, r0 = t >> 6;
#pragma unroll
  for (int i = 0; i < 16; ++i) {
    int r = i * 4 + r0;
    tile[c][r] = __float2bfloat16(W[(size_t)(tk + r) * 4096 + tn + c]);
  }
  __syncthreads();
#pragma unroll
  for (int i = 0; i < 16; ++i) {
    int r = i * 4 + r0;
    WT[(size_t)(tn + r) * 4096 + tk + c] = tile[r][c];
  }
}

// ---------------- Fused Q+K GEMM: A via LDS, B register-direct from global ----------------
// BM=BN=256, BK=64; 8 waves (2m x 4n), wave tile 128x64 (acc[8][4]).
// A: LDS 2 bufs x 2 kc-blocks [256][32] = 64 KB (-> 2 blocks/CU).
// B: no LDS (zero cross-wave reuse) — per-lane global loads double-buffered one
// half-tile ahead (compiler auto-waits the data dep).
// Per half: {4 b-loads + 2 gload_lds} above a sched_barrier(0) pin, MFMA x32,
// vmcnt(6) (drains all stages older than this half), s_barrier. 2 barriers/K-tile.
// 2D XCD chunk. Epilogue: bn<16 -> Q (RoPE+scale), else K (RoPE).
__global__ __launch_bounds__(512) void gemmQK9(const bf16* __restrict__ A,
                                               const bf16* __restrict__ Bt,
                                               bf16* __restrict__ Qb,
                                               bf16* __restrict__ Kb,
                                               const float* __restrict__ fcos,
                                               const float* __restrict__ fsin) {
  __shared__ bf16 LDS[2 * 16384];  // 64 KB: buf*16384 + kc*8192
  const int K = 4096, NK = 64;
  int g = blockIdx.x;
  int xcd = g & 7, loc = g >> 3;
  int bm = (xcd >> 2) * 4 + (loc >> 3);
  int bn = (xcd & 3) * 8 + (loc & 7);
  int t = threadIdx.x, lane = t & 63, w = t >> 6;
  int wm = w >> 2, wn = w & 3;
  int lr = lane & 15, lg = lane >> 4;
  int rsw = (lr >> 1) & 3;
  f32x4 acc[8][4] = {};

  const bf16* Ab = A + (size_t)bm * 256 * K;
  const bf16* Bb = Bt + (size_t)bn * 256 * K;
  int sr4 = t >> 2;
  int sg = (t & 3) ^ ((t >> 3) & 3);

  // per-lane B row pointers (B-operand fragment rows owned exclusively by this wave)
  const bf16* brow[4];
#pragma unroll
  for (int nf = 0; nf < 4; ++nf)
    brow[nf] = Bb + (size_t)(wn * 64 + nf * 16 + lr) * K + lg * 8;

#define SA(nb, kt2, kh)                                                          \
  do {                                                                           \
    _Pragma("unroll") for (int j = 0; j < 2; ++j)                                \
      gload_lds16(Ab + (size_t)(j * 128 + sr4) * K + (kt2) * 64 + (kh) * 32 + sg * 8, \
                  LDS + (nb) + (kh) * 8192 + (j * 512 + t) * 8);                 \
  } while (0)
#define AFR(base, kc, mi) \
  (*(const short8*)(LDS + (base) + (kc) * 8192 + (wm * 128 + (mi) * 16 + lr) * 32 + ((lg ^ rsw) << 3)))

  short8 b0[4], b1[4];
  // prologue: stage A tile0 (both halves), load b(tile0, kc0)
  SA(0, 0, 0); SA(0, 0, 1);
#pragma unroll
  for (int nf = 0; nf < 4; ++nf) b0[nf] = *(const short8*)(brow[nf]);
  asm volatile("s_waitcnt vmcnt(6)" ::: "memory");  // SA(0,h0) drained
  __builtin_amdgcn_s_barrier();

  int cur = 0;
  for (int kt = 0; kt < NK; ++kt) {
    int base = cur * 16384;
    int nbf = (cur ^ 1) * 16384;
    bool pf = (kt + 1) < NK;

    // ---- half kc=0: consume b0; load b1 (this tile kc=1); stage SA(kt+1, h0) ----
#pragma unroll
    for (int nf = 0; nf < 4; ++nf)
      b1[nf] = *(const short8*)(brow[nf] + kt * 64 + 32);
    if (pf) SA(nbf, kt + 1, 0);
    {
      short8 a[4];
#pragma unroll
      for (int i = 0; i < 4; ++i) a[i] = AFR(base, 0, i);
      __builtin_amdgcn_s_setprio(1);
#pragma unroll
      for (int i = 0; i < 4; ++i)
#pragma unroll
        for (int nf = 0; nf < 4; ++nf)
          acc[i][nf] = MFMA16(a[i], b0[nf], acc[i][nf]);
      __builtin_amdgcn_s_setprio(0);
#pragma unroll
      for (int i = 0; i < 4; ++i) a[i] = AFR(base, 0, 4 + i);
      __builtin_amdgcn_s_setprio(1);
#pragma unroll
      for (int i = 0; i < 4; ++i)
#pragma unroll
        for (int nf = 0; nf < 4; ++nf)
          acc[4 + i][nf] = MFMA16(a[i], b0[nf], acc[4 + i][nf]);
      __builtin_amdgcn_s_setprio(0);
    }
    __builtin_amdgcn_sched_barrier(0);
    asm volatile("s_waitcnt vmcnt(6)" ::: "memory");  // all pre-this-half stages drained
    __builtin_amdgcn_s_barrier();

    // ---- half kc=1: consume b1; load b0 (next tile kc=0); stage SA(kt+1, h1) ----
    int ktn = pf ? kt + 1 : kt;  // clamped (tail reload, discarded)
#pragma unroll
    for (int nf = 0; nf < 4; ++nf)
      b0[nf] = *(const short8*)(brow[nf] + ktn * 64);
    if (pf) SA(nbf, kt + 1, 1);
    {
      short8 a[4];
#pragma unroll
      for (int i = 0; i < 4; ++i) a[i] = AFR(base, 1, i);
      __builtin_amdgcn_s_setprio(1);
#pragma unroll
      for (int i = 0; i < 4; ++i)
#pragma unroll
        for (int nf = 0; nf < 4; ++nf)
          acc[i][nf] = MFMA16(a[i], b1[nf], acc[i][nf]);
      __builtin_amdgcn_s_setprio(0);
#pragma unroll
      for (int i = 0; i < 4; ++i) a[i] = AFR(base, 1, 4 + i);
      __builtin_amdgcn_s_setprio(1);
#pragma unroll
      for (int i = 0; i < 4; ++i)
#pragma unroll
        for (int nf = 0; nf < 4; ++nf)
          acc[4 + i][nf] = MFMA16(a[i], b1[nf], acc[4 + i][nf]);
      __builtin_amdgcn_s_setprio(0);
    }
    __builtin_amdgcn_sched_barrier(0);
    asm volatile("s_waitcnt vmcnt(6)" ::: "memory");
    __builtin_amdgcn_s_barrier();

    cur ^= 1;
  }
#undef SA
#undef AFR

  int sect = bn >> 4, bnl = bn & 15;
  bf16* Cb = sect ? Kb : Qb;
  const float qs = sect ? 1.0f : 0.08838834764831845f;
#pragma unroll
  for (int mi = 0; mi < 8; ++mi)
#pragma unroll
    for (int nf = 0; nf < 4; ++nf) {
      int col = bnl * 256 + wn * 64 + nf * 16 + lr;
      int row0 = bm * 256 + wm * 128 + mi * 16 + lg * 4;
      int ip = (col >> 1) & 63;
      float sgn = (col & 1) ? 1.0f : -1.0f;
#pragma unroll
      for (int r = 0; r < 4; ++r) {
        int row = row0 + r;
        float mine = acc[mi][nf][r];
        float oth = __shfl_xor(mine, 1);
        float cv = fcos[row * 64 + ip];
        float sv = fsin[row * 64 + ip];
        float v = (mine * cv + sgn * oth * sv) * qs;
        Cb[(size_t)row * 4096 + col] = __float2bfloat16(v);
      }
    }
}

// ---------------- gemmB2: BM=128 BN=256; A via LDS (32 KB), B register-direct ----------
// 8 waves = 1x8, wave tile 128x32 (acc[8][2]). Per half: {2 b-loads + 1 gload_lds},
// pin, MFMA x16, vmcnt(3), barrier. EPI: 3 = Vt[col][row] store, 4 = fp32 store.
template <int EPI>
__global__ __launch_bounds__(512) void gemmB2(const bf16* __restrict__ A,
                                              const bf16* __restrict__ Bt,
                                              void* __restrict__ Cv,
                                              int M, int N) {
  __shared__ bf16 LDS[2 * 8192];  // 32 KB: buf*8192 + kc*4096
  const int K = 4096, NK = 64;
  int g = blockIdx.x;
  int xcd = g & 7, loc = g >> 3;
  int bm = (xcd >> 1) * 4 + (loc >> 3);
  int bn = (xcd & 1) * 8 + (loc & 7);
  int t = threadIdx.x, lane = t & 63, w = t >> 6;
  int lr = lane & 15, lg = lane >> 4;
  int rsw = (lr >> 1) & 3;
  f32x4 acc[8][2] = {};

  const bf16* Ab = A + (size_t)bm * 128 * K;
  const bf16* Bb = Bt + (size_t)bn * 256 * K;
  int sr4 = t >> 2;
  int sg = (t & 3) ^ ((t >> 3) & 3);

  const bf16* brow[2];
#pragma unroll
  for (int nf = 0; nf < 2; ++nf)
    brow[nf] = Bb + (size_t)(w * 32 + nf * 16 + lr) * K + lg * 8;

#define SAB(nb, kt2, kh)                                                         \
  gload_lds16(Ab + (size_t)sr4 * K + (kt2) * 64 + (kh) * 32 + sg * 8,            \
              LDS + (nb) + (kh) * 4096 + t * 8)
#define AFRB(base, kc, mi) \
  (*(const short8*)(LDS + (base) + (kc) * 4096 + ((mi) * 16 + lr) * 32 + ((lg ^ rsw) << 3)))

  short8 b0[2], b1[2];
  SAB(0, 0, 0); SAB(0, 0, 1);
#pragma unroll
  for (int nf = 0; nf < 2; ++nf) b0[nf] = *(const short8*)(brow[nf]);
  asm volatile("s_waitcnt vmcnt(3)" ::: "memory");  // SA(0,h0) drained
  __builtin_amdgcn_s_barrier();

  int cur = 0;
  for (int kt = 0; kt < NK; ++kt) {
    int base = cur * 8192;
    int nbf = (cur ^ 1) * 8192;
    bool pf = (kt + 1) < NK;

    // ---- half kc=0 ----
#pragma unroll
    for (int nf = 0; nf < 2; ++nf)
      b1[nf] = *(const short8*)(brow[nf] + kt * 64 + 32);
    if (pf) SAB(nbf, kt + 1, 0);
    {
      short8 a[4];
#pragma unroll
      for (int i = 0; i < 4; ++i) a[i] = AFRB(base, 0, i);
      __builtin_amdgcn_s_setprio(1);
#pragma unroll
      for (int i = 0; i < 4; ++i)
#pragma unroll
        for (int nf = 0; nf < 2; ++nf)
          acc[i][nf] = MFMA16(a[i], b0[nf], acc[i][nf]);
      __builtin_amdgcn_s_setprio(0);
#pragma unroll
      for (int i = 0; i < 4; ++i) a[i] = AFRB(base, 0, 4 + i);
      __builtin_amdgcn_s_setprio(1);
#pragma unroll
      for (int i = 0; i < 4; ++i)
#pragma unroll
        for (int nf = 0; nf < 2; ++nf)
          acc[4 + i][nf] = MFMA16(a[i], b0[nf], acc[4 + i][nf]);
      __builtin_amdgcn_s_setprio(0);
    }
    __builtin_amdgcn_sched_barrier(0);
    asm volatile("s_waitcnt vmcnt(3)" ::: "memory");
    __builtin_amdgcn_s_barrier();

    // ---- half kc=1 ----
    int ktn = pf ? kt + 1 : kt;
#pragma unroll
    for (int nf = 0; nf < 2; ++nf)
      b0[nf] = *(const short8*)(brow[nf] + ktn * 64);
    if (pf) SAB(nbf, kt + 1, 1);
    {
      short8 a[4];
#pragma unroll
      for (int i = 0; i < 4; ++i) a[i] = AFRB(base, 1, i);
      __builtin_amdgcn_s_setprio(1);
#pragma unroll
      for (int i = 0; i < 4; ++i)
#pragma unroll
        for (int nf = 0; nf < 2; ++nf)
          acc[i][nf] = MFMA16(a[i], b1[nf], acc[i][nf]);
      __builtin_amdgcn_s_setprio(0);
#pragma unroll
      for (int i = 0; i < 4; ++i) a[i] = AFRB(base, 1, 4 + i);
      __builtin_amdgcn_s_setprio(1);
#pragma unroll
      for (int i = 0; i < 4; ++i)
#pragma unroll
        for (int nf = 0; nf < 2; ++nf)
          acc[4 + i][nf] = MFMA16(a[i], b1[nf], acc[4 + i][nf]);
      __builtin_amdgcn_s_setprio(0);
    }
    __builtin_amdgcn_sched_barrier(0);
    asm volatile("s_waitcnt vmcnt(3)" ::: "memory");
    __builtin_amdgcn_s_barrier();

    cur ^= 1;
  }
#undef SAB
#undef AFRB

#pragma unroll
  for (int mi = 0; mi < 8; ++mi)
#pragma unroll
    for (int nf = 0; nf < 2; ++nf) {
      int col = bn * 256 + w * 32 + nf * 16 + lr;
      int row0 = bm * 128 + mi * 16 + lg * 4;
      if constexpr (EPI == 3) {
        bf16 tmp[4];
#pragma unroll
        for (int r = 0; r < 4; ++r) tmp[r] = __float2bfloat16(acc[mi][nf][r]);
        *(short4v*)((bf16*)Cv + (size_t)col * M + row0) = *(short4v*)tmp;
      } else {
#pragma unroll
        for (int r = 0; r < 4; ++r)
          ((float*)Cv)[(size_t)(row0 + r) * N + col] = acc[mi][nf][r];
      }
    }
}

// ---------------- Flash attention v3 (unchanged) ----------------
__global__ __launch_bounds__(512, 2) void attn_fwd(const bf16* __restrict__ Q,
                                                   const bf16* __restrict__ K,
                                                   const bf16* __restrict__ Vt,
                                                   bf16* __restrict__ O) {
  __shared__ bf16 Kbuf[2][64 * 128];
  __shared__ bf16 Vbuf[2][128 * 64];
  __shared__ char Ps_all[8][2][2048];
  const int S = 2048, D = 4096, HD = 128, NT = 32;
  int g = blockIdx.y * 8 + blockIdx.x;
  int wid = (g & 7) * 32 + (g >> 3);
  int h = wid >> 3, qb = wid & 7;
  int tid = threadIdx.x, lane = tid & 63, w = tid >> 6;
  int lr = lane & 15, lg = lane >> 4;
  int q0 = qb * 256 + w * 32;
  int swz = (lr & 7) << 4;

  const bf16* Kh = K + h * HD;
  const bf16* Vh = Vt + (size_t)h * HD * S;

  short8 aq[2][4];
#pragma unroll
  for (int u = 0; u < 2; ++u)
#pragma unroll
    for (int c = 0; c < 4; ++c)
      aq[u][c] = *(const short8*)(Q + (size_t)(q0 + u * 16 + lr) * D + h * HD + c * 32 + lg * 8);

  int kr = lane >> 4, ksl = lane & 15;
  int vr = lane >> 3, vsl = lane & 7;

  f32x4 accO[2][8] = {};
  float lsum[2] = {0.f, 0.f};

#define STAGE(b, ttile)                                                            \
  do {                                                                             \
    int kv0_ = (ttile) * 64;                                                       \
    _Pragma("unroll") for (int ii = 0; ii < 2; ++ii) {                             \
      int row = w * 8 + ii * 4 + kr;                                               \
      gload_lds16(Kh + (size_t)(kv0_ + row) * D + ((ksl ^ (row & 7)) << 3),        \
                  &Kbuf[b][(w * 8 + ii * 4) * 128]);                               \
    }                                                                              \
    _Pragma("unroll") for (int ii = 0; ii < 2; ++ii) {                             \
      int row = w * 16 + ii * 8 + vr;                                              \
      gload_lds16(Vh + (size_t)row * S + kv0_ + ((vsl ^ (row & 7)) << 3),          \
                  &Vbuf[b][(w * 16 + ii * 8) * 64]);                               \
    }                                                                              \
  } while (0)

  int cur = 0;
  STAGE(0, 0);
  for (int tt = 0; tt < NT; ++tt) {
    if (tt + 1 < NT) {
      STAGE(cur ^ 1, tt + 1);
      asm volatile("s_waitcnt vmcnt(4)" ::: "memory");
    } else {
      asm volatile("s_waitcnt vmcnt(0)" ::: "memory");
    }
    __builtin_amdgcn_s_barrier();
    const bf16* Kb_ = Kbuf[cur];
    const bf16* Vb_ = Vbuf[cur];

    f32x4 sf[2][4] = {};
#pragma unroll
    for (int j = 0; j < 4; ++j)
#pragma unroll
      for (int c = 0; c < 4; ++c) {
        short8 kf = *(const short8*)(Kb_ + (j * 16 + lr) * 128 +
                                     (((c * 4 + lg) ^ (lr & 7)) << 3));
        sf[0][j] = MFMA16(kf, aq[0][c], sf[0][j]);
        sf[1][j] = MFMA16(kf, aq[1][c], sf[1][j]);
      }
#pragma unroll
    for (int u = 0; u < 2; ++u) {
      char* Ps = Ps_all[w][u];
#pragma unroll
      for (int j = 0; j < 4; ++j) {
        float p0 = __expf(sf[u][j][0]);
        float p1 = __expf(sf[u][j][1]);
        float p2 = __expf(sf[u][j][2]);
        float p3 = __expf(sf[u][j][3]);
        lsum[u] += (p0 + p1) + (p2 + p3);
        bf16 pk[4] = {__float2bfloat16(p0), __float2bfloat16(p1),
                      __float2bfloat16(p2), __float2bfloat16(p3)};
        *(short4v*)(Ps + lr * 128 + ((j * 32 + lg * 8) ^ swz)) = *(short4v*)pk;
      }
    }
#pragma unroll
    for (int t2 = 0; t2 < 2; ++t2) {
      short8 pa0 = *(const short8*)(Ps_all[w][0] + lr * 128 + ((t2 * 64 + lg * 16) ^ swz));
      short8 pa1 = *(const short8*)(Ps_all[w][1] + lr * 128 + ((t2 * 64 + lg * 16) ^ swz));
#pragma unroll
      for (int n = 0; n < 8; ++n) {
        short8 bv = *(const short8*)(Vb_ + (n * 16 + lr) * 64 +
                                     (((t2 * 4 + lg) ^ (lr & 7)) << 3));
        accO[0][n] = MFMA16(pa0, bv, accO[0][n]);
        accO[1][n] = MFMA16(pa1, bv, accO[1][n]);
      }
    }
    __builtin_amdgcn_s_barrier();
    cur ^= 1;
  }
#undef STAGE

#pragma unroll
  for (int u = 0; u < 2; ++u) {
    float ls = lsum[u];
    ls += __shfl_xor(ls, 16);
    ls += __shfl_xor(ls, 32);
    float rs[4];
#pragma unroll
    for (int r = 0; r < 4; ++r)
      rs[r] = 1.f / __shfl(ls, lg * 4 + r);
#pragma unroll
    for (int n = 0; n < 8; ++n)
#pragma unroll
      for (int r = 0; r < 4; ++r) {
        int row = q0 + u * 16 + lg * 4 + r;
        int col = h * HD + n * 16 + lr;
        O[(size_t)row * D + col] = __float2bfloat16(accO[u][n][r] * rs[r]);
      }
  }
}

extern "C" void kernel_launch(void* const* d_in, const int* in_sizes, int n_in,
                              void* d_out, int out_size, void* d_ws, size_t ws_size,
                              hipStream_t stream) {
  const float* x    = (const float*)d_in[0];
  const float* fcos = (const float*)d_in[1];
  const float* fsin = (const float*)d_in[2];
  const float* wq   = (const float*)d_in[3];
  const float* wk   = (const float*)d_in[4];
  const float* wv   = (const float*)d_in[5];
  const float* wo   = (const float*)d_in[6];
  float* out = (float*)d_out;

  const int S = 2048, D = 4096;
  const size_t MB = 1024 * 1024;
  char* ws = (char*)d_ws;
  bf16* xb  = (bf16*)(ws);            // [0,16)  x bf16; later AO
  bf16* wT2 = (bf16*)(ws + 16 * MB);  // [16,80) wq-T | wk-T; later wv-T / wo-T
  bf16* Vt  = (bf16*)(ws + 48 * MB);  // [48,80) Vt[h][d][s]
  bf16* Qb  = (bf16*)(ws + 80 * MB);  // [80,96)
  bf16* Kb  = (bf16*)(ws + 96 * MB);  // [96,112)
  bf16* AO  = (bf16*)(ws);            // reuse xb slot after QKV GEMMs

  int n = S * D;
  castx_kernel<<<n / (256 * 8), 256, 0, stream>>>(x, xb, n);

  // fused Q+K GEMM (N=8192), B-register-direct
  tw_kernel<<<4096, 256, 0, stream>>>(wq, wT2);
  tw_kernel<<<4096, 256, 0, stream>>>(wk, wT2 + (size_t)4096 * 4096);
  gemmQK9<<<256, 512, 0, stream>>>(xb, wT2, Qb, Kb, fcos, fsin);

  // V GEMM with transposed store
  tw_kernel<<<4096, 256, 0, stream>>>(wv, wT2);
  gemmB2<3><<<256, 512, 0, stream>>>(xb, wT2, Vt, S, D);

  attn_fwd<<<dim3(8, 32), 512, 0, stream>>>(Qb, Kb, Vt, AO);

  // output GEMM (fp32 out)
  tw_kernel<<<4096, 256, 0, stream>>>(wo, wT2);
  gemmB2<4><<<256, 512, 0, stream>>>(AO, wT2, out, S, D);
}

// Round 14
// 406.503 us; speedup vs baseline: 1.7454x; 1.3245x over previous
//
#include <hip/hip_runtime.h>
#include <hip/hip_bf16.h>

typedef __hip_bfloat16 bf16;
typedef __attribute__((ext_vector_type(8))) short short8;
typedef __attribute__((ext_vector_type(4))) short short4v;
typedef __attribute__((ext_vector_type(4))) float f32x4;

#define MFMA16(a, b, c) __builtin_amdgcn_mfma_f32_16x16x32_bf16((a), (b), (c), 0, 0, 0)

static __device__ __forceinline__ void gload_lds16(const bf16* g, bf16* l) {
  __builtin_amdgcn_global_load_lds((const __attribute__((address_space(1))) unsigned int*)g,
                                   (__attribute__((address_space(3))) unsigned int*)l,
                                   16, 0, 0);
}

// ---------------- prep3: y=0 -> tw(wq), y=1 -> tw(wk), y=2 -> castx ----------------
__global__ __launch_bounds__(256) void prep3_kernel(const float* __restrict__ x,
                                                    bf16* __restrict__ xb,
                                                    const float* __restrict__ wq,
                                                    const float* __restrict__ wk,
                                                    bf16* __restrict__ wT2) {
  if (blockIdx.y == 2) {
    int i = (blockIdx.x * 256 + threadIdx.x) * 8;
    float4 v0 = *(const float4*)(x + i);
    float4 v1 = *(const float4*)(x + i + 4);
    bf16 tmp[8];
    tmp[0] = __float2bfloat16(v0.x); tmp[1] = __float2bfloat16(v0.y);
    tmp[2] = __float2bfloat16(v0.z); tmp[3] = __float2bfloat16(v0.w);
    tmp[4] = __float2bfloat16(v1.x); tmp[5] = __float2bfloat16(v1.y);
    tmp[6] = __float2bfloat16(v1.z); tmp[7] = __float2bfloat16(v1.w);
    *(short8*)(xb + i) = *(short8*)tmp;
    return;
  }
  const float* W = blockIdx.y ? wk : wq;
  bf16* WT = wT2 + (blockIdx.y ? (size_t)4096 * 4096 : 0);
  __shared__ bf16 tile[64][65];
  int b = blockIdx.x;
  int tk = (b >> 6) * 64;
  int tn = (b & 63) * 64;
  int t = threadIdx.x;
  int c = t & 63, r0 = t >> 6;
#pragma unroll
  for (int i = 0; i < 16; ++i) {
    int r = i * 4 + r0;
    tile[c][r] = __float2bfloat16(W[(size_t)(tk + r) * 4096 + tn + c]);
  }
  __syncthreads();
#pragma unroll
  for (int i = 0; i < 16; ++i) {
    int r = i * 4 + r0;
    WT[(size_t)(tn + r) * 4096 + tk + c] = tile[r][c];
  }
}

// ---------------- transpose+cast weight: W[K][N] fp32 -> WT[N][K] bf16 ----------------
__global__ __launch_bounds__(256) void tw_kernel(const float* __restrict__ W,
                                                 bf16* __restrict__ WT) {
  __shared__ bf16 tile[64][65];
  int b = blockIdx.x;
  int tk = (b >> 6) * 64;
  int tn = (b & 63) * 64;
  int t = threadIdx.x;
  int c = t & 63, r0 = t >> 6;
#pragma unroll
  for (int i = 0; i < 16; ++i) {
    int r = i * 4 + r0;
    tile[c][r] = __float2bfloat16(W[(size_t)(tk + r) * 4096 + tn + c]);
  }
  __syncthreads();
#pragma unroll
  for (int i = 0; i < 16; ++i) {
    int r = i * 4 + r0;
    WT[(size_t)(tn + r) * 4096 + tk + c] = tile[r][c];
  }
}

// ---------------- Fused Q+K GEMM (r11 exact): reduced-barrier schedule ----------------
// BM=BN=256, BK=64; 8 waves, wave 128x64. LDS 2 bufs x {A_k0,A_k1,B_k0,B_k1} [256][32].
// 2 barriers/K-tile (after counted vmcnt(4) drains); waves free-run between them.
// 2D XCD chunk (4bm x 8bn per XCD). Epilogue: bn<16 -> Q (RoPE+scale), else K (RoPE).
__global__ __launch_bounds__(512) void gemmQK8(const bf16* __restrict__ A,
                                               const bf16* __restrict__ Bt,
                                               bf16* __restrict__ Qb,
                                               bf16* __restrict__ Kb,
                                               const float* __restrict__ fcos,
                                               const float* __restrict__ fsin) {
  __shared__ bf16 LDS[2 * 32768];  // 128 KB
  const int K = 4096, NK = 64;
  int g = blockIdx.x;
  int xcd = g & 7, loc = g >> 3;
  int bm = (xcd >> 2) * 4 + (loc >> 3);
  int bn = (xcd & 3) * 8 + (loc & 7);
  int t = threadIdx.x, lane = t & 63, w = t >> 6;
  int wm = w >> 2, wn = w & 3;
  int lr = lane & 15, lg = lane >> 4;
  int rsw = (lr >> 1) & 3;
  f32x4 acc[8][4] = {};

  const bf16* Ab = A + (size_t)bm * 256 * K;
  const bf16* Bb = Bt + (size_t)bn * 256 * K;
  int sr4 = t >> 2;
  int sg = (t & 3) ^ ((t >> 3) & 3);

#define SA(nb, kt2, kh)                                                          \
  do {                                                                           \
    _Pragma("unroll") for (int j = 0; j < 2; ++j)                                \
      gload_lds16(Ab + (size_t)(j * 128 + sr4) * K + (kt2) * 64 + (kh) * 32 + sg * 8, \
                  LDS + (nb) + (kh) * 8192 + (j * 512 + t) * 8);                 \
  } while (0)
#define SB(nb, kt2, kh)                                                          \
  do {                                                                           \
    _Pragma("unroll") for (int j = 0; j < 2; ++j)                                \
      gload_lds16(Bb + (size_t)(j * 128 + sr4) * K + (kt2) * 64 + (kh) * 32 + sg * 8, \
                  LDS + (nb) + 16384 + (kh) * 8192 + (j * 512 + t) * 8);         \
  } while (0)
#define AFR(base, kc, mi) \
  (*(const short8*)(LDS + (base) + (kc) * 8192 + (wm * 128 + (mi) * 16 + lr) * 32 + ((lg ^ rsw) << 3)))
#define BFR(base, kc, nf) \
  (*(const short8*)(LDS + (base) + 16384 + (kc) * 8192 + (wn * 64 + (nf) * 16 + lr) * 32 + ((lg ^ rsw) << 3)))

  SA(0, 0, 0); SB(0, 0, 0); SA(0, 0, 1); SB(0, 0, 1);
  asm volatile("s_waitcnt vmcnt(4)" ::: "memory");
  __builtin_amdgcn_s_barrier();

  int cur = 0;
  for (int kt = 0; kt < NK; ++kt) {
    int base = cur * 32768;
    int nbf = (cur ^ 1) * 32768;
    bool pf = (kt + 1) < NK;
    short8 a[4], b[4];

    // ---- half kc=0 (free-run, no barriers inside) ----
#pragma unroll
    for (int nf = 0; nf < 4; ++nf) b[nf] = BFR(base, 0, nf);
#pragma unroll
    for (int i = 0; i < 4; ++i) a[i] = AFR(base, 0, i);
    if (pf) SA(nbf, kt + 1, 0);
    __builtin_amdgcn_s_setprio(1);
#pragma unroll
    for (int i = 0; i < 4; ++i)
#pragma unroll
      for (int nf = 0; nf < 4; ++nf)
        acc[i][nf] = MFMA16(a[i], b[nf], acc[i][nf]);
    __builtin_amdgcn_s_setprio(0);
#pragma unroll
    for (int i = 0; i < 4; ++i) a[i] = AFR(base, 0, 4 + i);
    if (pf) SB(nbf, kt + 1, 0);
    __builtin_amdgcn_s_setprio(1);
#pragma unroll
    for (int i = 0; i < 4; ++i)
#pragma unroll
      for (int nf = 0; nf < 4; ++nf)
        acc[4 + i][nf] = MFMA16(a[i], b[nf], acc[4 + i][nf]);
    __builtin_amdgcn_s_setprio(0);
    if (pf)
      asm volatile("s_waitcnt vmcnt(4)" ::: "memory");  // drain this tile's A_k1,B_k1
    else
      asm volatile("s_waitcnt vmcnt(0)" ::: "memory");
    __builtin_amdgcn_s_barrier();

    // ---- half kc=1 ----
#pragma unroll
    for (int nf = 0; nf < 4; ++nf) b[nf] = BFR(base, 1, nf);
#pragma unroll
    for (int i = 0; i < 4; ++i) a[i] = AFR(base, 1, i);
    if (pf) SA(nbf, kt + 1, 1);
    __builtin_amdgcn_s_setprio(1);
#pragma unroll
    for (int i = 0; i < 4; ++i)
#pragma unroll
      for (int nf = 0; nf < 4; ++nf)
        acc[i][nf] = MFMA16(a[i], b[nf], acc[i][nf]);
    __builtin_amdgcn_s_setprio(0);
#pragma unroll
    for (int i = 0; i < 4; ++i) a[i] = AFR(base, 1, 4 + i);
    if (pf) SB(nbf, kt + 1, 1);
    __builtin_amdgcn_s_setprio(1);
#pragma unroll
    for (int i = 0; i < 4; ++i)
#pragma unroll
      for (int nf = 0; nf < 4; ++nf)
        acc[4 + i][nf] = MFMA16(a[i], b[nf], acc[4 + i][nf]);
    __builtin_amdgcn_s_setprio(0);
    asm volatile("s_waitcnt vmcnt(4)" ::: "memory");  // drain next tile's A_k0,B_k0
    __builtin_amdgcn_s_barrier();

    cur ^= 1;
  }
#undef SA
#undef SB
#undef AFR
#undef BFR

  int sect = bn >> 4, bnl = bn & 15;
  bf16* Cb = sect ? Kb : Qb;
  const float qs = sect ? 1.0f : 0.08838834764831845f;
#pragma unroll
  for (int mi = 0; mi < 8; ++mi)
#pragma unroll
    for (int nf = 0; nf < 4; ++nf) {
      int col = bnl * 256 + wn * 64 + nf * 16 + lr;
      int row0 = bm * 256 + wm * 128 + mi * 16 + lg * 4;
      int ip = (col >> 1) & 63;
      float sgn = (col & 1) ? 1.0f : -1.0f;
#pragma unroll
      for (int r = 0; r < 4; ++r) {
        int row = row0 + r;
        float mine = acc[mi][nf][r];
        float oth = __shfl_xor(mine, 1);
        float cv = fcos[row * 64 + ip];
        float sv = fsin[row * 64 + ip];
        float v = (mine * cv + sgn * oth * sv) * qs;
        Cb[(size_t)row * 4096 + col] = __float2bfloat16(v);
      }
    }
}

// ---------------- gemmB (r11 exact): BM=128 BN=256 ----------
// 8 waves = 1x8, wave tile 128x32 (acc[8][2]); LDS 2 bufs x {A_k0,A_k1,B_k0,B_k1},
// 96 KB. 2 barriers/K-tile, vmcnt(3) counted drains.
// EPI: 3 = transposed store Vt[col][row] (bf16), 4 = fp32 store.
template <int EPI>
__global__ __launch_bounds__(512) void gemmB(const bf16* __restrict__ A,
                                             const bf16* __restrict__ Bt,
                                             void* __restrict__ Cv,
                                             int M, int N) {
  __shared__ bf16 LDS[2 * 24576];  // 96 KB
  const int K = 4096, NK = 64;
  int g = blockIdx.x;
  int xcd = g & 7, loc = g >> 3;
  int bm = (xcd >> 1) * 4 + (loc >> 3);
  int bn = (xcd & 1) * 8 + (loc & 7);
  int t = threadIdx.x, lane = t & 63, w = t >> 6;
  int lr = lane & 15, lg = lane >> 4;
  int rsw = (lr >> 1) & 3;
  f32x4 acc[8][2] = {};

  const bf16* Ab = A + (size_t)bm * 128 * K;
  const bf16* Bb = Bt + (size_t)bn * 256 * K;
  int sr4 = t >> 2;
  int sg = (t & 3) ^ ((t >> 3) & 3);

#define SAB(nb, kt2, kh)                                                         \
  gload_lds16(Ab + (size_t)sr4 * K + (kt2) * 64 + (kh) * 32 + sg * 8,            \
              LDS + (nb) + (kh) * 4096 + t * 8)
#define SBB(nb, kt2, kh)                                                         \
  do {                                                                           \
    _Pragma("unroll") for (int j = 0; j < 2; ++j)                                \
      gload_lds16(Bb + (size_t)(j * 128 + sr4) * K + (kt2) * 64 + (kh) * 32 + sg * 8, \
                  LDS + (nb) + 8192 + (kh) * 8192 + (j * 512 + t) * 8);          \
  } while (0)
#define AFRB(base, kc, mi) \
  (*(const short8*)(LDS + (base) + (kc) * 4096 + ((mi) * 16 + lr) * 32 + ((lg ^ rsw) << 3)))
#define BFRB(base, kc, nf) \
  (*(const short8*)(LDS + (base) + 8192 + (kc) * 8192 + (w * 32 + (nf) * 16 + lr) * 32 + ((lg ^ rsw) << 3)))

  SAB(0, 0, 0); SBB(0, 0, 0); SAB(0, 0, 1); SBB(0, 0, 1);
  asm volatile("s_waitcnt vmcnt(3)" ::: "memory");
  __builtin_amdgcn_s_barrier();

  int cur = 0;
  for (int kt = 0; kt < NK; ++kt) {
    int base = cur * 24576;
    int nbf = (cur ^ 1) * 24576;
    bool pf = (kt + 1) < NK;
    short8 a[8], b[2];

    // ---- half kc=0 ----
    b[0] = BFRB(base, 0, 0); b[1] = BFRB(base, 0, 1);
#pragma unroll
    for (int i = 0; i < 8; ++i) a[i] = AFRB(base, 0, i);
    if (pf) { SAB(nbf, kt + 1, 0); SBB(nbf, kt + 1, 0); }
    if (pf)
      asm volatile("s_waitcnt vmcnt(3)" ::: "memory");
    else
      asm volatile("s_waitcnt vmcnt(0)" ::: "memory");
    __builtin_amdgcn_s_barrier();
    __builtin_amdgcn_s_setprio(1);
#pragma unroll
    for (int i = 0; i < 8; ++i)
#pragma unroll
      for (int nf = 0; nf < 2; ++nf)
        acc[i][nf] = MFMA16(a[i], b[nf], acc[i][nf]);
    __builtin_amdgcn_s_setprio(0);

    // ---- half kc=1 ----
    b[0] = BFRB(base, 1, 0); b[1] = BFRB(base, 1, 1);
#pragma unroll
    for (int i = 0; i < 8; ++i) a[i] = AFRB(base, 1, i);
    if (pf) { SAB(nbf, kt + 1, 1); SBB(nbf, kt + 1, 1); }
    asm volatile("s_waitcnt vmcnt(3)" ::: "memory");
    __builtin_amdgcn_s_barrier();
    __builtin_amdgcn_s_setprio(1);
#pragma unroll
    for (int i = 0; i < 8; ++i)
#pragma unroll
      for (int nf = 0; nf < 2; ++nf)
        acc[i][nf] = MFMA16(a[i], b[nf], acc[i][nf]);
    __builtin_amdgcn_s_setprio(0);

    cur ^= 1;
  }
#undef SAB
#undef SBB
#undef AFRB
#undef BFRB

#pragma unroll
  for (int mi = 0; mi < 8; ++mi)
#pragma unroll
    for (int nf = 0; nf < 2; ++nf) {
      int col = bn * 256 + w * 32 + nf * 16 + lr;
      int row0 = bm * 128 + mi * 16 + lg * 4;
      if constexpr (EPI == 3) {
        bf16 tmp[4];
#pragma unroll
        for (int r = 0; r < 4; ++r) tmp[r] = __float2bfloat16(acc[mi][nf][r]);
        *(short4v*)((bf16*)Cv + (size_t)col * M + row0) = *(short4v*)tmp;
      } else {
#pragma unroll
        for (int r = 0; r < 4; ++r)
          ((float*)Cv)[(size_t)(row0 + r) * N + col] = acc[mi][nf][r];
      }
    }
}

// ---------------- Flash attention v3 + T5 setprio ----------------
__global__ __launch_bounds__(512, 2) void attn_fwd(const bf16* __restrict__ Q,
                                                   const bf16* __restrict__ K,
                                                   const bf16* __restrict__ Vt,
                                                   bf16* __restrict__ O) {
  __shared__ bf16 Kbuf[2][64 * 128];
  __shared__ bf16 Vbuf[2][128 * 64];
  __shared__ char Ps_all[8][2][2048];
  const int S = 2048, D = 4096, HD = 128, NT = 32;
  int g = blockIdx.y * 8 + blockIdx.x;
  int wid = (g & 7) * 32 + (g >> 3);
  int h = wid >> 3, qb = wid & 7;
  int tid = threadIdx.x, lane = tid & 63, w = tid >> 6;
  int lr = lane & 15, lg = lane >> 4;
  int q0 = qb * 256 + w * 32;
  int swz = (lr & 7) << 4;

  const bf16* Kh = K + h * HD;
  const bf16* Vh = Vt + (size_t)h * HD * S;

  short8 aq[2][4];
#pragma unroll
  for (int u = 0; u < 2; ++u)
#pragma unroll
    for (int c = 0; c < 4; ++c)
      aq[u][c] = *(const short8*)(Q + (size_t)(q0 + u * 16 + lr) * D + h * HD + c * 32 + lg * 8);

  int kr = lane >> 4, ksl = lane & 15;
  int vr = lane >> 3, vsl = lane & 7;

  f32x4 accO[2][8] = {};
  float lsum[2] = {0.f, 0.f};

#define STAGE(b, ttile)                                                            \
  do {                                                                             \
    int kv0_ = (ttile) * 64;                                                       \
    _Pragma("unroll") for (int ii = 0; ii < 2; ++ii) {                             \
      int row = w * 8 + ii * 4 + kr;                                               \
      gload_lds16(Kh + (size_t)(kv0_ + row) * D + ((ksl ^ (row & 7)) << 3),        \
                  &Kbuf[b][(w * 8 + ii * 4) * 128]);                               \
    }                                                                              \
    _Pragma("unroll") for (int ii = 0; ii < 2; ++ii) {                             \
      int row = w * 16 + ii * 8 + vr;                                              \
      gload_lds16(Vh + (size_t)row * S + kv0_ + ((vsl ^ (row & 7)) << 3),          \
                  &Vbuf[b][(w * 16 + ii * 8) * 64]);                               \
    }                                                                              \
  } while (0)

  int cur = 0;
  STAGE(0, 0);
  for (int tt = 0; tt < NT; ++tt) {
    if (tt + 1 < NT) {
      STAGE(cur ^ 1, tt + 1);
      asm volatile("s_waitcnt vmcnt(4)" ::: "memory");
    } else {
      asm volatile("s_waitcnt vmcnt(0)" ::: "memory");
    }
    __builtin_amdgcn_s_barrier();
    const bf16* Kb_ = Kbuf[cur];
    const bf16* Vb_ = Vbuf[cur];

    f32x4 sf[2][4] = {};
    __builtin_amdgcn_s_setprio(1);
#pragma unroll
    for (int j = 0; j < 4; ++j)
#pragma unroll
      for (int c = 0; c < 4; ++c) {
        short8 kf = *(const short8*)(Kb_ + (j * 16 + lr) * 128 +
                                     (((c * 4 + lg) ^ (lr & 7)) << 3));
        sf[0][j] = MFMA16(kf, aq[0][c], sf[0][j]);
        sf[1][j] = MFMA16(kf, aq[1][c], sf[1][j]);
      }
    __builtin_amdgcn_s_setprio(0);
#pragma unroll
    for (int u = 0; u < 2; ++u) {
      char* Ps = Ps_all[w][u];
#pragma unroll
      for (int j = 0; j < 4; ++j) {
        float p0 = __expf(sf[u][j][0]);
        float p1 = __expf(sf[u][j][1]);
        float p2 = __expf(sf[u][j][2]);
        float p3 = __expf(sf[u][j][3]);
        lsum[u] += (p0 + p1) + (p2 + p3);
        bf16 pk[4] = {__float2bfloat16(p0), __float2bfloat16(p1),
                      __float2bfloat16(p2), __float2bfloat16(p3)};
        *(short4v*)(Ps + lr * 128 + ((j * 32 + lg * 8) ^ swz)) = *(short4v*)pk;
      }
    }
#pragma unroll
    for (int t2 = 0; t2 < 2; ++t2) {
      short8 pa0 = *(const short8*)(Ps_all[w][0] + lr * 128 + ((t2 * 64 + lg * 16) ^ swz));
      short8 pa1 = *(const short8*)(Ps_all[w][1] + lr * 128 + ((t2 * 64 + lg * 16) ^ swz));
      __builtin_amdgcn_s_setprio(1);
#pragma unroll
      for (int n = 0; n < 8; ++n) {
        short8 bv = *(const short8*)(Vb_ + (n * 16 + lr) * 64 +
                                     (((t2 * 4 + lg) ^ (lr & 7)) << 3));
        accO[0][n] = MFMA16(pa0, bv, accO[0][n]);
        accO[1][n] = MFMA16(pa1, bv, accO[1][n]);
      }
      __builtin_amdgcn_s_setprio(0);
    }
    __builtin_amdgcn_s_barrier();
    cur ^= 1;
  }
#undef STAGE

#pragma unroll
  for (int u = 0; u < 2; ++u) {
    float ls = lsum[u];
    ls += __shfl_xor(ls, 16);
    ls += __shfl_xor(ls, 32);
    float rs[4];
#pragma unroll
    for (int r = 0; r < 4; ++r)
      rs[r] = 1.f / __shfl(ls, lg * 4 + r);
#pragma unroll
    for (int n = 0; n < 8; ++n)
#pragma unroll
      for (int r = 0; r < 4; ++r) {
        int row = q0 + u * 16 + lg * 4 + r;
        int col = h * HD + n * 16 + lr;
        O[(size_t)row * D + col] = __float2bfloat16(accO[u][n][r] * rs[r]);
      }
  }
}

extern "C" void kernel_launch(void* const* d_in, const int* in_sizes, int n_in,
                              void* d_out, int out_size, void* d_ws, size_t ws_size,
                              hipStream_t stream) {
  const float* x    = (const float*)d_in[0];
  const float* fcos = (const float*)d_in[1];
  const float* fsin = (const float*)d_in[2];
  const float* wq   = (const float*)d_in[3];
  const float* wk   = (const float*)d_in[4];
  const float* wv   = (const float*)d_in[5];
  const float* wo   = (const float*)d_in[6];
  float* out = (float*)d_out;

  const int S = 2048, D = 4096;
  const size_t MB = 1024 * 1024;
  char* ws = (char*)d_ws;
  bf16* xb  = (bf16*)(ws);            // [0,16)  x bf16; later AO
  bf16* wT2 = (bf16*)(ws + 16 * MB);  // [16,80) wq-T | wk-T; later wv-T / wo-T
  bf16* Vt  = (bf16*)(ws + 48 * MB);  // [48,80) Vt[h][d][s]
  bf16* Qb  = (bf16*)(ws + 80 * MB);  // [80,96)
  bf16* Kb  = (bf16*)(ws + 96 * MB);  // [96,112)
  bf16* AO  = (bf16*)(ws);            // reuse xb slot after QKV GEMMs

  // fused prep: castx + tw(wq) + tw(wk) in one launch
  prep3_kernel<<<dim3(4096, 3), 256, 0, stream>>>(x, xb, wq, wk, wT2);
  gemmQK8<<<256, 512, 0, stream>>>(xb, wT2, Qb, Kb, fcos, fsin);

  // V GEMM with transposed store (gemmB, 256 blocks)
  tw_kernel<<<4096, 256, 0, stream>>>(wv, wT2);
  gemmB<3><<<256, 512, 0, stream>>>(xb, wT2, Vt, S, D);

  attn_fwd<<<dim3(8, 32), 512, 0, stream>>>(Qb, Kb, Vt, AO);

  // output GEMM (fp32 out, gemmB, 256 blocks)
  tw_kernel<<<4096, 256, 0, stream>>>(wo, wT2);
  gemmB<4><<<256, 512, 0, stream>>>(AO, wT2, out, S, D);
}

// Round 15
// 398.038 us; speedup vs baseline: 1.7826x; 1.0213x over previous
//
#include <hip/hip_runtime.h>
#include <hip/hip_bf16.h>

typedef __hip_bfloat16 bf16;
typedef __attribute__((ext_vector_type(8))) short short8;
typedef __attribute__((ext_vector_type(4))) short short4v;
typedef __attribute__((ext_vector_type(4))) float f32x4;

#define MFMA16(a, b, c) __builtin_amdgcn_mfma_f32_16x16x32_bf16((a), (b), (c), 0, 0, 0)

static __device__ __forceinline__ void gload_lds16(const bf16* g, bf16* l) {
  __builtin_amdgcn_global_load_lds((const __attribute__((address_space(1))) unsigned int*)g,
                                   (__attribute__((address_space(3))) unsigned int*)l,
                                   16, 0, 0);
}

// ---------------- prep3: y=0 -> tw(wq), y=1 -> tw(wk), y=2 -> castx ----------------
__global__ __launch_bounds__(256) void prep3_kernel(const float* __restrict__ x,
                                                    bf16* __restrict__ xb,
                                                    const float* __restrict__ wq,
                                                    const float* __restrict__ wk,
                                                    bf16* __restrict__ wT2) {
  if (blockIdx.y == 2) {
    int i = (blockIdx.x * 256 + threadIdx.x) * 8;
    float4 v0 = *(const float4*)(x + i);
    float4 v1 = *(const float4*)(x + i + 4);
    bf16 tmp[8];
    tmp[0] = __float2bfloat16(v0.x); tmp[1] = __float2bfloat16(v0.y);
    tmp[2] = __float2bfloat16(v0.z); tmp[3] = __float2bfloat16(v0.w);
    tmp[4] = __float2bfloat16(v1.x); tmp[5] = __float2bfloat16(v1.y);
    tmp[6] = __float2bfloat16(v1.z); tmp[7] = __float2bfloat16(v1.w);
    *(short8*)(xb + i) = *(short8*)tmp;
    return;
  }
  const float* W = blockIdx.y ? wk : wq;
  bf16* WT = wT2 + (blockIdx.y ? (size_t)4096 * 4096 : 0);
  __shared__ bf16 tile[64][65];
  int b = blockIdx.x;
  int tk = (b >> 6) * 64;
  int tn = (b & 63) * 64;
  int t = threadIdx.x;
  int c = t & 63, r0 = t >> 6;
#pragma unroll
  for (int i = 0; i < 16; ++i) {
    int r = i * 4 + r0;
    tile[c][r] = __float2bfloat16(W[(size_t)(tk + r) * 4096 + tn + c]);
  }
  __syncthreads();
#pragma unroll
  for (int i = 0; i < 16; ++i) {
    int r = i * 4 + r0;
    WT[(size_t)(tn + r) * 4096 + tk + c] = tile[r][c];
  }
}

// ---------------- transpose+cast weight: W[K][N] fp32 -> WT[N][K] bf16 ----------------
__global__ __launch_bounds__(256) void tw_kernel(const float* __restrict__ W,
                                                 bf16* __restrict__ WT) {
  __shared__ bf16 tile[64][65];
  int b = blockIdx.x;
  int tk = (b >> 6) * 64;
  int tn = (b & 63) * 64;
  int t = threadIdx.x;
  int c = t & 63, r0 = t >> 6;
#pragma unroll
  for (int i = 0; i < 16; ++i) {
    int r = i * 4 + r0;
    tile[c][r] = __float2bfloat16(W[(size_t)(tk + r) * 4096 + tn + c]);
  }
  __syncthreads();
#pragma unroll
  for (int i = 0; i < 16; ++i) {
    int r = i * 4 + r0;
    WT[(size_t)(tn + r) * 4096 + tk + c] = tile[r][c];
  }
}

// ---------------- Fused Q+K GEMM (r11/r14 exact): reduced-barrier schedule ----------------
__global__ __launch_bounds__(512) void gemmQK8(const bf16* __restrict__ A,
                                               const bf16* __restrict__ Bt,
                                               bf16* __restrict__ Qb,
                                               bf16* __restrict__ Kb,
                                               const float* __restrict__ fcos,
                                               const float* __restrict__ fsin) {
  __shared__ bf16 LDS[2 * 32768];  // 128 KB
  const int K = 4096, NK = 64;
  int g = blockIdx.x;
  int xcd = g & 7, loc = g >> 3;
  int bm = (xcd >> 2) * 4 + (loc >> 3);
  int bn = (xcd & 3) * 8 + (loc & 7);
  int t = threadIdx.x, lane = t & 63, w = t >> 6;
  int wm = w >> 2, wn = w & 3;
  int lr = lane & 15, lg = lane >> 4;
  int rsw = (lr >> 1) & 3;
  f32x4 acc[8][4] = {};

  const bf16* Ab = A + (size_t)bm * 256 * K;
  const bf16* Bb = Bt + (size_t)bn * 256 * K;
  int sr4 = t >> 2;
  int sg = (t & 3) ^ ((t >> 3) & 3);

#define SA(nb, kt2, kh)                                                          \
  do {                                                                           \
    _Pragma("unroll") for (int j = 0; j < 2; ++j)                                \
      gload_lds16(Ab + (size_t)(j * 128 + sr4) * K + (kt2) * 64 + (kh) * 32 + sg * 8, \
                  LDS + (nb) + (kh) * 8192 + (j * 512 + t) * 8);                 \
  } while (0)
#define SB(nb, kt2, kh)                                                          \
  do {                                                                           \
    _Pragma("unroll") for (int j = 0; j < 2; ++j)                                \
      gload_lds16(Bb + (size_t)(j * 128 + sr4) * K + (kt2) * 64 + (kh) * 32 + sg * 8, \
                  LDS + (nb) + 16384 + (kh) * 8192 + (j * 512 + t) * 8);         \
  } while (0)
#define AFR(base, kc, mi) \
  (*(const short8*)(LDS + (base) + (kc) * 8192 + (wm * 128 + (mi) * 16 + lr) * 32 + ((lg ^ rsw) << 3)))
#define BFR(base, kc, nf) \
  (*(const short8*)(LDS + (base) + 16384 + (kc) * 8192 + (wn * 64 + (nf) * 16 + lr) * 32 + ((lg ^ rsw) << 3)))

  SA(0, 0, 0); SB(0, 0, 0); SA(0, 0, 1); SB(0, 0, 1);
  asm volatile("s_waitcnt vmcnt(4)" ::: "memory");
  __builtin_amdgcn_s_barrier();

  int cur = 0;
  for (int kt = 0; kt < NK; ++kt) {
    int base = cur * 32768;
    int nbf = (cur ^ 1) * 32768;
    bool pf = (kt + 1) < NK;
    short8 a[4], b[4];

    // ---- half kc=0 (free-run, no barriers inside) ----
#pragma unroll
    for (int nf = 0; nf < 4; ++nf) b[nf] = BFR(base, 0, nf);
#pragma unroll
    for (int i = 0; i < 4; ++i) a[i] = AFR(base, 0, i);
    if (pf) SA(nbf, kt + 1, 0);
    __builtin_amdgcn_s_setprio(1);
#pragma unroll
    for (int i = 0; i < 4; ++i)
#pragma unroll
      for (int nf = 0; nf < 4; ++nf)
        acc[i][nf] = MFMA16(a[i], b[nf], acc[i][nf]);
    __builtin_amdgcn_s_setprio(0);
#pragma unroll
    for (int i = 0; i < 4; ++i) a[i] = AFR(base, 0, 4 + i);
    if (pf) SB(nbf, kt + 1, 0);
    __builtin_amdgcn_s_setprio(1);
#pragma unroll
    for (int i = 0; i < 4; ++i)
#pragma unroll
      for (int nf = 0; nf < 4; ++nf)
        acc[4 + i][nf] = MFMA16(a[i], b[nf], acc[4 + i][nf]);
    __builtin_amdgcn_s_setprio(0);
    if (pf)
      asm volatile("s_waitcnt vmcnt(4)" ::: "memory");
    else
      asm volatile("s_waitcnt vmcnt(0)" ::: "memory");
    __builtin_amdgcn_s_barrier();

    // ---- half kc=1 ----
#pragma unroll
    for (int nf = 0; nf < 4; ++nf) b[nf] = BFR(base, 1, nf);
#pragma unroll
    for (int i = 0; i < 4; ++i) a[i] = AFR(base, 1, i);
    if (pf) SA(nbf, kt + 1, 1);
    __builtin_amdgcn_s_setprio(1);
#pragma unroll
    for (int i = 0; i < 4; ++i)
#pragma unroll
      for (int nf = 0; nf < 4; ++nf)
        acc[i][nf] = MFMA16(a[i], b[nf], acc[i][nf]);
    __builtin_amdgcn_s_setprio(0);
#pragma unroll
    for (int i = 0; i < 4; ++i) a[i] = AFR(base, 1, 4 + i);
    if (pf) SB(nbf, kt + 1, 1);
    __builtin_amdgcn_s_setprio(1);
#pragma unroll
    for (int i = 0; i < 4; ++i)
#pragma unroll
      for (int nf = 0; nf < 4; ++nf)
        acc[4 + i][nf] = MFMA16(a[i], b[nf], acc[4 + i][nf]);
    __builtin_amdgcn_s_setprio(0);
    asm volatile("s_waitcnt vmcnt(4)" ::: "memory");
    __builtin_amdgcn_s_barrier();

    cur ^= 1;
  }
#undef SA
#undef SB
#undef AFR
#undef BFR

  int sect = bn >> 4, bnl = bn & 15;
  bf16* Cb = sect ? Kb : Qb;
  const float qs = sect ? 1.0f : 0.08838834764831845f;
#pragma unroll
  for (int mi = 0; mi < 8; ++mi)
#pragma unroll
    for (int nf = 0; nf < 4; ++nf) {
      int col = bnl * 256 + wn * 64 + nf * 16 + lr;
      int row0 = bm * 256 + wm * 128 + mi * 16 + lg * 4;
      int ip = (col >> 1) & 63;
      float sgn = (col & 1) ? 1.0f : -1.0f;
#pragma unroll
      for (int r = 0; r < 4; ++r) {
        int row = row0 + r;
        float mine = acc[mi][nf][r];
        float oth = __shfl_xor(mine, 1);
        float cv = fcos[row * 64 + ip];
        float sv = fsin[row * 64 + ip];
        float v = (mine * cv + sgn * oth * sv) * qs;
        Cb[(size_t)row * 4096 + col] = __float2bfloat16(v);
      }
    }
}

// ---------------- gemmB3: half-height QK8 clone. BM=128 BN=256, wave 64x64 ----------
// 8 waves (2m x 4n), acc[4][4]. LDS 2 bufs x {A[128][32] x2kc, B[256][32] x2kc} = 96 KB.
// QK8's free-run order: reads -> stage -> MFMA -> counted vmcnt(3) -> barrier.
// Ledger: prologue 6 instr, drain to 3 (kc0 ready). Per half issue 3 (SA 1 + SB 2),
// drain 3 -> exactly one half-tile crosses each barrier in flight.
// EPI: 3 = transposed store Vt[col][row] (bf16), 4 = fp32 store.
template <int EPI>
__global__ __launch_bounds__(512) void gemmB3(const bf16* __restrict__ A,
                                              const bf16* __restrict__ Bt,
                                              void* __restrict__ Cv,
                                              int M, int N) {
  __shared__ bf16 LDS[2 * 24576];  // 96 KB: buf*24576 + {A: kc*4096, B: 8192 + kc*8192}
  const int K = 4096, NK = 64;
  int g = blockIdx.x;
  int xcd = g & 7, loc = g >> 3;
  int bm = (xcd >> 1) * 4 + (loc >> 3);  // [0,16)
  int bn = (xcd & 1) * 8 + (loc & 7);    // [0,16)
  int t = threadIdx.x, lane = t & 63, w = t >> 6;
  int wm = w >> 2, wn = w & 3;           // wave tile rows wm*64, cols wn*64
  int lr = lane & 15, lg = lane >> 4;
  int rsw = (lr >> 1) & 3;
  f32x4 acc[4][4] = {};

  const bf16* Ab = A + (size_t)bm * 128 * K;
  const bf16* Bb = Bt + (size_t)bn * 256 * K;
  int sr4 = t >> 2;
  int sg = (t & 3) ^ ((t >> 3) & 3);

#define SAB(nb, kt2, kh)                                                         \
  gload_lds16(Ab + (size_t)sr4 * K + (kt2) * 64 + (kh) * 32 + sg * 8,            \
              LDS + (nb) + (kh) * 4096 + t * 8)
#define SBB(nb, kt2, kh)                                                         \
  do {                                                                           \
    _Pragma("unroll") for (int j = 0; j < 2; ++j)                                \
      gload_lds16(Bb + (size_t)(j * 128 + sr4) * K + (kt2) * 64 + (kh) * 32 + sg * 8, \
                  LDS + (nb) + 8192 + (kh) * 8192 + (j * 512 + t) * 8);          \
  } while (0)
#define AFRB(base, kc, mi) \
  (*(const short8*)(LDS + (base) + (kc) * 4096 + ((wm * 64 + (mi) * 16 + lr) * 32) + ((lg ^ rsw) << 3)))
#define BFRB(base, kc, nf) \
  (*(const short8*)(LDS + (base) + 8192 + (kc) * 8192 + (wn * 64 + (nf) * 16 + lr) * 32 + ((lg ^ rsw) << 3)))

  SAB(0, 0, 0); SBB(0, 0, 0); SAB(0, 0, 1); SBB(0, 0, 1);
  asm volatile("s_waitcnt vmcnt(3)" ::: "memory");  // kc0's {SA,SB} ready
  __builtin_amdgcn_s_barrier();

  int cur = 0;
  for (int kt = 0; kt < NK; ++kt) {
    int base = cur * 24576;
    int nbf = (cur ^ 1) * 24576;
    bool pf = (kt + 1) < NK;
    short8 a[4], b[4];

    // ---- half kc=0: reads -> stage -> MFMA -> drain -> barrier ----
#pragma unroll
    for (int nf = 0; nf < 4; ++nf) b[nf] = BFRB(base, 0, nf);
#pragma unroll
    for (int i = 0; i < 4; ++i) a[i] = AFRB(base, 0, i);
    if (pf) { SAB(nbf, kt + 1, 0); SBB(nbf, kt + 1, 0); }
    __builtin_amdgcn_s_setprio(1);
#pragma unroll
    for (int i = 0; i < 4; ++i)
#pragma unroll
      for (int nf = 0; nf < 4; ++nf)
        acc[i][nf] = MFMA16(a[i], b[nf], acc[i][nf]);
    __builtin_amdgcn_s_setprio(0);
    if (pf)
      asm volatile("s_waitcnt vmcnt(3)" ::: "memory");  // drain this tile's kc1 stages
    else
      asm volatile("s_waitcnt vmcnt(0)" ::: "memory");
    __builtin_amdgcn_s_barrier();

    // ---- half kc=1 ----
#pragma unroll
    for (int nf = 0; nf < 4; ++nf) b[nf] = BFRB(base, 1, nf);
#pragma unroll
    for (int i = 0; i < 4; ++i) a[i] = AFRB(base, 1, i);
    if (pf) { SAB(nbf, kt + 1, 1); SBB(nbf, kt + 1, 1); }
    __builtin_amdgcn_s_setprio(1);
#pragma unroll
    for (int i = 0; i < 4; ++i)
#pragma unroll
      for (int nf = 0; nf < 4; ++nf)
        acc[i][nf] = MFMA16(a[i], b[nf], acc[i][nf]);
    __builtin_amdgcn_s_setprio(0);
    asm volatile("s_waitcnt vmcnt(3)" ::: "memory");  // drain next tile's kc0 stages
    __builtin_amdgcn_s_barrier();

    cur ^= 1;
  }
#undef SAB
#undef SBB
#undef AFRB
#undef BFRB

#pragma unroll
  for (int mi = 0; mi < 4; ++mi)
#pragma unroll
    for (int nf = 0; nf < 4; ++nf) {
      int col = bn * 256 + wn * 64 + nf * 16 + lr;
      int row0 = bm * 128 + wm * 64 + mi * 16 + lg * 4;
      if constexpr (EPI == 3) {
        bf16 tmp[4];
#pragma unroll
        for (int r = 0; r < 4; ++r) tmp[r] = __float2bfloat16(acc[mi][nf][r]);
        *(short4v*)((bf16*)Cv + (size_t)col * M + row0) = *(short4v*)tmp;
      } else {
#pragma unroll
        for (int r = 0; r < 4; ++r)
          ((float*)Cv)[(size_t)(row0 + r) * N + col] = acc[mi][nf][r];
      }
    }
}

// ---------------- Flash attention v3 + T5 setprio (r14 exact) ----------------
__global__ __launch_bounds__(512, 2) void attn_fwd(const bf16* __restrict__ Q,
                                                   const bf16* __restrict__ K,
                                                   const bf16* __restrict__ Vt,
                                                   bf16* __restrict__ O) {
  __shared__ bf16 Kbuf[2][64 * 128];
  __shared__ bf16 Vbuf[2][128 * 64];
  __shared__ char Ps_all[8][2][2048];
  const int S = 2048, D = 4096, HD = 128, NT = 32;
  int g = blockIdx.y * 8 + blockIdx.x;
  int wid = (g & 7) * 32 + (g >> 3);
  int h = wid >> 3, qb = wid & 7;
  int tid = threadIdx.x, lane = tid & 63, w = tid >> 6;
  int lr = lane & 15, lg = lane >> 4;
  int q0 = qb * 256 + w * 32;
  int swz = (lr & 7) << 4;

  const bf16* Kh = K + h * HD;
  const bf16* Vh = Vt + (size_t)h * HD * S;

  short8 aq[2][4];
#pragma unroll
  for (int u = 0; u < 2; ++u)
#pragma unroll
    for (int c = 0; c < 4; ++c)
      aq[u][c] = *(const short8*)(Q + (size_t)(q0 + u * 16 + lr) * D + h * HD + c * 32 + lg * 8);

  int kr = lane >> 4, ksl = lane & 15;
  int vr = lane >> 3, vsl = lane & 7;

  f32x4 accO[2][8] = {};
  float lsum[2] = {0.f, 0.f};

#define STAGE(b, ttile)                                                            \
  do {                                                                             \
    int kv0_ = (ttile) * 64;                                                       \
    _Pragma("unroll") for (int ii = 0; ii < 2; ++ii) {                             \
      int row = w * 8 + ii * 4 + kr;                                               \
      gload_lds16(Kh + (size_t)(kv0_ + row) * D + ((ksl ^ (row & 7)) << 3),        \
                  &Kbuf[b][(w * 8 + ii * 4) * 128]);                               \
    }                                                                              \
    _Pragma("unroll") for (int ii = 0; ii < 2; ++ii) {                             \
      int row = w * 16 + ii * 8 + vr;                                              \
      gload_lds16(Vh + (size_t)row * S + kv0_ + ((vsl ^ (row & 7)) << 3),          \
                  &Vbuf[b][(w * 16 + ii * 8) * 64]);                               \
    }                                                                              \
  } while (0)

  int cur = 0;
  STAGE(0, 0);
  for (int tt = 0; tt < NT; ++tt) {
    if (tt + 1 < NT) {
      STAGE(cur ^ 1, tt + 1);
      asm volatile("s_waitcnt vmcnt(4)" ::: "memory");
    } else {
      asm volatile("s_waitcnt vmcnt(0)" ::: "memory");
    }
    __builtin_amdgcn_s_barrier();
    const bf16* Kb_ = Kbuf[cur];
    const bf16* Vb_ = Vbuf[cur];

    f32x4 sf[2][4] = {};
    __builtin_amdgcn_s_setprio(1);
#pragma unroll
    for (int j = 0; j < 4; ++j)
#pragma unroll
      for (int c = 0; c < 4; ++c) {
        short8 kf = *(const short8*)(Kb_ + (j * 16 + lr) * 128 +
                                     (((c * 4 + lg) ^ (lr & 7)) << 3));
        sf[0][j] = MFMA16(kf, aq[0][c], sf[0][j]);
        sf[1][j] = MFMA16(kf, aq[1][c], sf[1][j]);
      }
    __builtin_amdgcn_s_setprio(0);
#pragma unroll
    for (int u = 0; u < 2; ++u) {
      char* Ps = Ps_all[w][u];
#pragma unroll
      for (int j = 0; j < 4; ++j) {
        float p0 = __expf(sf[u][j][0]);
        float p1 = __expf(sf[u][j][1]);
        float p2 = __expf(sf[u][j][2]);
        float p3 = __expf(sf[u][j][3]);
        lsum[u] += (p0 + p1) + (p2 + p3);
        bf16 pk[4] = {__float2bfloat16(p0), __float2bfloat16(p1),
                      __float2bfloat16(p2), __float2bfloat16(p3)};
        *(short4v*)(Ps + lr * 128 + ((j * 32 + lg * 8) ^ swz)) = *(short4v*)pk;
      }
    }
#pragma unroll
    for (int t2 = 0; t2 < 2; ++t2) {
      short8 pa0 = *(const short8*)(Ps_all[w][0] + lr * 128 + ((t2 * 64 + lg * 16) ^ swz));
      short8 pa1 = *(const short8*)(Ps_all[w][1] + lr * 128 + ((t2 * 64 + lg * 16) ^ swz));
      __builtin_amdgcn_s_setprio(1);
#pragma unroll
      for (int n = 0; n < 8; ++n) {
        short8 bv = *(const short8*)(Vb_ + (n * 16 + lr) * 64 +
                                     (((t2 * 4 + lg) ^ (lr & 7)) << 3));
        accO[0][n] = MFMA16(pa0, bv, accO[0][n]);
        accO[1][n] = MFMA16(pa1, bv, accO[1][n]);
      }
      __builtin_amdgcn_s_setprio(0);
    }
    __builtin_amdgcn_s_barrier();
    cur ^= 1;
  }
#undef STAGE

#pragma unroll
  for (int u = 0; u < 2; ++u) {
    float ls = lsum[u];
    ls += __shfl_xor(ls, 16);
    ls += __shfl_xor(ls, 32);
    float rs[4];
#pragma unroll
    for (int r = 0; r < 4; ++r)
      rs[r] = 1.f / __shfl(ls, lg * 4 + r);
#pragma unroll
    for (int n = 0; n < 8; ++n)
#pragma unroll
      for (int r = 0; r < 4; ++r) {
        int row = q0 + u * 16 + lg * 4 + r;
        int col = h * HD + n * 16 + lr;
        O[(size_t)row * D + col] = __float2bfloat16(accO[u][n][r] * rs[r]);
      }
  }
}

extern "C" void kernel_launch(void* const* d_in, const int* in_sizes, int n_in,
                              void* d_out, int out_size, void* d_ws, size_t ws_size,
                              hipStream_t stream) {
  const float* x    = (const float*)d_in[0];
  const float* fcos = (const float*)d_in[1];
  const float* fsin = (const float*)d_in[2];
  const float* wq   = (const float*)d_in[3];
  const float* wk   = (const float*)d_in[4];
  const float* wv   = (const float*)d_in[5];
  const float* wo   = (const float*)d_in[6];
  float* out = (float*)d_out;

  const int S = 2048, D = 4096;
  const size_t MB = 1024 * 1024;
  char* ws = (char*)d_ws;
  bf16* xb  = (bf16*)(ws);            // [0,16)  x bf16; later AO
  bf16* wT2 = (bf16*)(ws + 16 * MB);  // [16,80) wq-T | wk-T; later wv-T / wo-T
  bf16* Vt  = (bf16*)(ws + 48 * MB);  // [48,80) Vt[h][d][s]
  bf16* Qb  = (bf16*)(ws + 80 * MB);  // [80,96)
  bf16* Kb  = (bf16*)(ws + 96 * MB);  // [96,112)
  bf16* AO  = (bf16*)(ws);            // reuse xb slot after QKV GEMMs

  // fused prep: castx + tw(wq) + tw(wk) in one launch
  prep3_kernel<<<dim3(4096, 3), 256, 0, stream>>>(x, xb, wq, wk, wT2);
  gemmQK8<<<256, 512, 0, stream>>>(xb, wT2, Qb, Kb, fcos, fsin);

  // V GEMM with transposed store (gemmB3, 256 blocks)
  tw_kernel<<<4096, 256, 0, stream>>>(wv, wT2);
  gemmB3<3><<<256, 512, 0, stream>>>(xb, wT2, Vt, S, D);

  attn_fwd<<<dim3(8, 32), 512, 0, stream>>>(Qb, Kb, Vt, AO);

  // output GEMM (fp32 out, gemmB3, 256 blocks)
  tw_kernel<<<4096, 256, 0, stream>>>(wo, wT2);
  gemmB3<4><<<256, 512, 0, stream>>>(AO, wT2, out, S, D);
}